// Round 7
// baseline (475.808 us; speedup 1.0000x reference)
//
#include <hip/hip_runtime.h>
#include <hip/hip_bf16.h>
#include <stdint.h>

typedef __attribute__((ext_vector_type(8))) short short8;
typedef __attribute__((ext_vector_type(4))) float f32x4;

#define D 256

static __device__ __forceinline__ float b2f(unsigned short u) {
  union { unsigned u; float f; } c; c.u = ((unsigned)u) << 16; return c.f;
}
static __device__ __forceinline__ unsigned f2b(float f) {
  union { float f; unsigned u; } c; c.f = f;
  return (c.u + 0x7FFFu + ((c.u >> 16) & 1u)) >> 16;
}

// async global->LDS, 16B per lane, wave-uniform LDS base + lane*16
static __device__ __forceinline__ void gload16(const void* g, void* l) {
  __builtin_amdgcn_global_load_lds(
      (const __attribute__((address_space(1))) unsigned int*)g,
      (__attribute__((address_space(3))) unsigned int*)l, 16, 0, 0);
}

// ---- fused convert: x (fp32->bf16, pad) + W transpose (W[r][i][o]->Wt[ro][i])
__global__ void k_cvt_xw(const float* __restrict__ x, unsigned short* __restrict__ xb,
                         long n_elems, long pad_elems, int xblocks,
                         const float* __restrict__ w, unsigned short* __restrict__ wt) {
  if (blockIdx.x < (unsigned)xblocks) {
    long i4 = (long)blockIdx.x * 256 + threadIdx.x;
    if (i4 * 4 >= pad_elems) return;
    ushort4 o;
    if (i4 * 4 < n_elems) {
      float4 v = ((const float4*)x)[i4];
      o.x = f2b(v.x); o.y = f2b(v.y); o.z = f2b(v.z); o.w = f2b(v.w);
    } else {
      o.x = 0; o.y = 0; o.z = 0; o.w = 0;
    }
    ((ushort4*)xb)[i4] = o;
  } else {
    int t = (blockIdx.x - xblocks) * 256 + threadIdx.x;
    int i = t & 255;         // k index
    int orow = t >> 8;       // r*256 + o
    int r = orow >> 8, o = orow & 255;
    wt[t] = (unsigned short)f2b(w[((size_t)(r * 256 + i)) * 256 + o]);
  }
}

// ---------------- CSR build over keys = row*8 + type (400k bins) ----------
__global__ void k_deg2(const int* __restrict__ ei, const int* __restrict__ et,
                       int* deg, int E) {
  int e = blockIdx.x * 256 + threadIdx.x;
  if (e < E) atomicAdd(&deg[ei[e] * 8 + et[e]], 1);
}
__global__ void k_scan1(const int* __restrict__ deg, int* bsum, int n) {
  __shared__ int sm[256];
  int t = threadIdx.x, idx = blockIdx.x * 256 + t;
  sm[t] = idx < n ? deg[idx] : 0;
  __syncthreads();
  for (int off = 128; off; off >>= 1) {
    if (t < off) sm[t] += sm[t + off];
    __syncthreads();
  }
  if (t == 0) bsum[blockIdx.x] = sm[0];
}
// scan of up to 2048 block-sums in one block (each thread handles 8 serial)
__global__ void k_scan2b(const int* __restrict__ bsum, int* __restrict__ boff,
                         int* __restrict__ rp_end, int nsc) {
  __shared__ int sm[256];
  int t = threadIdx.x;
  int loc[8];
  int s = 0;
#pragma unroll
  for (int j = 0; j < 8; ++j) {
    int idx = t * 8 + j;
    loc[j] = s;
    s += (idx < nsc) ? bsum[idx] : 0;
  }
  sm[t] = s;
  __syncthreads();
  for (int off = 1; off < 256; off <<= 1) {
    int x = t >= off ? sm[t - off] : 0;
    __syncthreads();
    sm[t] += x;
    __syncthreads();
  }
  int base = sm[t] - s;  // exclusive prefix of this thread's chunk
#pragma unroll
  for (int j = 0; j < 8; ++j) {
    int idx = t * 8 + j;
    if (idx < nsc) boff[idx] = base + loc[j];
  }
  if (t == 255) *rp_end = sm[255];
}
__global__ void k_scan3(const int* __restrict__ deg, const int* __restrict__ boff,
                        int* rowptr, int* cursor, int n) {
  __shared__ int sm[256];
  int t = threadIdx.x, idx = blockIdx.x * 256 + t;
  int v = idx < n ? deg[idx] : 0;
  sm[t] = v;
  __syncthreads();
  for (int off = 1; off < 256; off <<= 1) {
    int x = t >= off ? sm[t - off] : 0;
    __syncthreads();
    sm[t] += x;
    __syncthreads();
  }
  if (idx < n) {
    int e = boff[blockIdx.x] + sm[t] - v;
    rowptr[idx] = e;
    cursor[idx] = e;
  }
}
__global__ void k_bin2(const int* __restrict__ ei, const int* __restrict__ et,
                       int* cursor, int* ecol, int E) {
  int e = blockIdx.x * 256 + threadIdx.x;
  if (e >= E) return;
  int key = ei[e] * 8 + et[e];
  int pos = atomicAdd(&cursor[key], 1);
  ecol[pos] = ei[E + e];
}

// ---------------- fused aggregate(+)GEMM:  out = relu(bias + sum_r H_r @ W_r)
// H_r[row,:] = sum_{edges (row,r)} x[col,:]  built per relation in LDS from
// L2-resident xb (25.6 MB), consumed immediately by MFMA — H never hits HBM.
// Block: 32 rows x 256 out-cols, K = 8 relations x 256. 4 waves, wave-tile
// [32 m x 64 n] (acc 2x4). LDS 48 KB -> 3 blocks/CU, grid 1563 ~ 2.03 rounds.
// lH [32][256] bf16 swizzled (chunk ^ row&7); lB [256 n][64 k] staged per
// k-step via gload16 w/ inverse-swizzled source (proven k_gemm pattern).
__global__ __launch_bounds__(256) void k_fused(const unsigned short* __restrict__ xb,
                                               const unsigned short* __restrict__ Wt,
                                               const int* __restrict__ rp2,
                                               const int* __restrict__ ecol,
                                               const float* __restrict__ bias,
                                               float* __restrict__ out, int Nn) {
  __shared__ __align__(16) char lds[32 * 512 + 256 * 128];  // lH 16KB + lB 32KB
  char* lH = lds;
  char* lB = lds + 32 * 512;
  const int t = threadIdx.x;
  const int lane = t & 63;
  const int wave = t >> 6;
  const int l15 = lane & 15, lhi = lane >> 4;
  const int half = lane >> 5, sl = lane & 31;
  const int tm = blockIdx.x * 32;

  f32x4 acc[2][4];
#pragma unroll
  for (int a = 0; a < 2; ++a)
#pragma unroll
    for (int b = 0; b < 4; ++b)
#pragma unroll
      for (int e = 0; e < 4; ++e) acc[a][b][e] = 0.f;

  for (int r = 0; r < 8; ++r) {
    __syncthreads();  // previous relation's lH readers done
    // ---- gather H_r: wave owns rows [wave*8, wave*8+8), 2 rows in lane-halves
#pragma unroll
    for (int pr = 0; pr < 4; ++pr) {
      int hr = wave * 8 + pr * 2 + half;
      int row = tm + hr;
      float a[8] = {0.f, 0.f, 0.f, 0.f, 0.f, 0.f, 0.f, 0.f};
      if (row < Nn) {
        int key = row * 8 + r;
        int s = rp2[key], e = rp2[key + 1];
        for (int i = s; i < e; ++i) {
          int col = ecol[i];
          short8 v = *(const short8*)(xb + (size_t)col * 256 + sl * 8);
#pragma unroll
          for (int k = 0; k < 8; ++k) a[k] += b2f((unsigned short)v[k]);
        }
      }
      uint4 pk;
      pk.x = f2b(a[0]) | (f2b(a[1]) << 16);
      pk.y = f2b(a[2]) | (f2b(a[3]) << 16);
      pk.z = f2b(a[4]) | (f2b(a[5]) << 16);
      pk.w = f2b(a[6]) | (f2b(a[7]) << 16);
      *(uint4*)(lH + hr * 512 + ((sl ^ (hr & 7)) * 16)) = pk;
    }
    // ---- MFMA over this relation's K=256 (4 k-steps of 64)
    for (int kt = 0; kt < 256; kt += 64) {
      __syncthreads();  // kt==0: lH writes visible; else: prev lB readers done
#pragma unroll
      for (int it = 0; it < 8; ++it) {
        int s2 = it * 256 + t;
        int nrow = s2 >> 3, c = s2 & 7;
        gload16(Wt + ((size_t)(r * 256 + nrow)) * 256 + kt + ((c ^ (nrow & 7)) * 8),
                lB + (it * 256 + wave * 64) * 16);
      }
      __syncthreads();  // barrier drains vmcnt: lB ready

      const int ktc = kt >> 3;
      short8 af[2][2];
#pragma unroll
      for (int mi = 0; mi < 2; ++mi)
#pragma unroll
        for (int kk = 0; kk < 2; ++kk) {
          int R = mi * 16 + l15;
          int c = ktc + kk * 4 + lhi;
          af[mi][kk] = *(const short8*)(lH + R * 512 + ((c ^ (R & 7)) * 16));
        }
#pragma unroll
      for (int ni = 0; ni < 4; ++ni) {
        int R2 = wave * 64 + ni * 16 + l15;
        short8 b0 = *(const short8*)(lB + R2 * 128 + ((lhi ^ (R2 & 7)) * 16));
        short8 b1 = *(const short8*)(lB + R2 * 128 + (((4 + lhi) ^ (R2 & 7)) * 16));
#pragma unroll
        for (int mi = 0; mi < 2; ++mi) {
          acc[mi][ni] = __builtin_amdgcn_mfma_f32_16x16x32_bf16(af[mi][0], b0, acc[mi][ni], 0, 0, 0);
          acc[mi][ni] = __builtin_amdgcn_mfma_f32_16x16x32_bf16(af[mi][1], b1, acc[mi][ni], 0, 0, 0);
        }
      }
    }
  }
  // ---- epilogue: bounce acc through LDS (f32 [32][stride 260]) for coalesced
  // float4 out stores. 260: float4-aligned reads, 2-way-max scatter conflicts.
  __syncthreads();  // all lH/lB readers done; reuse lds as f32 bounce
  float* bz = (float*)lds;
#pragma unroll
  for (int mi = 0; mi < 2; ++mi)
#pragma unroll
    for (int ni = 0; ni < 4; ++ni)
#pragma unroll
      for (int j = 0; j < 4; ++j)
        bz[(mi * 16 + lhi * 4 + j) * 260 + wave * 64 + ni * 16 + l15] = acc[mi][ni][j];
  __syncthreads();
  const float4* b4 = (const float4*)bias;
#pragma unroll
  for (int it = 0; it < 8; ++it) {
    int idx = it * 256 + t;
    int r32 = idx >> 6, seg = idx & 63;
    int row = tm + r32;
    if (row < Nn) {
      float4 v = *(const float4*)(bz + r32 * 260 + seg * 4);
      float4 bb = b4[seg];
      float4 o;
      o.x = fmaxf(v.x + bb.x, 0.f);
      o.y = fmaxf(v.y + bb.y, 0.f);
      o.z = fmaxf(v.z + bb.z, 0.f);
      o.w = fmaxf(v.w + bb.w, 0.f);
      ((float4*)out)[(size_t)row * 64 + seg] = o;
    }
  }
}

extern "C" void kernel_launch(void* const* d_in, const int* in_sizes, int n_in,
                              void* d_out, int out_size, void* d_ws, size_t ws_size,
                              hipStream_t stream) {
  const float* x = (const float*)d_in[0];
  const int* ei = (const int*)d_in[1];
  const int* et = (const int*)d_in[2];
  const float* w = (const float*)d_in[3];
  const float* bias = (const float*)d_in[4];
  float* out = (float*)d_out;

  const int Nn = in_sizes[0] / D;        // 50000
  const int E = in_sizes[2];             // 800000
  const int R = in_sizes[3] / (D * D);   // 8
  const int M32 = (Nn + 31) / 32;        // 1563 blocks for k_fused
  const int Mpad = M32 * 32;             // 50016
  const int NC = R * D;                  // 2048
  const int n2 = Nn * R;                 // 400000 bins

  char* p = (char*)d_ws;
  auto alloc = [&](size_t bytes) -> char* {
    char* q = p;
    p += (bytes + 255) & ~(size_t)255;
    return q;
  };
  unsigned short* xb = (unsigned short*)alloc((size_t)Mpad * D * 2);
  unsigned short* wt = (unsigned short*)alloc((size_t)NC * D * 2);
  int* rp2 = (int*)alloc((size_t)(n2 + 1) * 4);
  int* cursor2 = (int*)alloc((size_t)n2 * 4);
  int* deg2 = (int*)alloc((size_t)n2 * 4);
  int* bsum = (int*)alloc(2048 * 4);
  int* boff = (int*)alloc(2048 * 4);
  int* ecol = (int*)alloc((size_t)E * 4);

  const int nsc2 = (n2 + 255) / 256;     // 1563
  const int xblocks = Mpad / 4;

  // CSR build over (row, type) bins
  hipMemsetAsync(deg2, 0, (size_t)n2 * 4, stream);
  hipLaunchKernelGGL(k_deg2, dim3((E + 255) / 256), dim3(256), 0, stream, ei, et, deg2, E);
  hipLaunchKernelGGL(k_scan1, dim3(nsc2), dim3(256), 0, stream, deg2, bsum, n2);
  hipLaunchKernelGGL(k_scan2b, dim3(1), dim3(256), 0, stream, bsum, boff, rp2 + n2, nsc2);
  hipLaunchKernelGGL(k_scan3, dim3(nsc2), dim3(256), 0, stream, deg2, boff, rp2, cursor2, n2);
  hipLaunchKernelGGL(k_bin2, dim3((E + 255) / 256), dim3(256), 0, stream, ei, et, cursor2, ecol, E);

  // converts
  hipLaunchKernelGGL(k_cvt_xw, dim3(xblocks + (NC * D) / 256), dim3(256), 0, stream,
                     x, xb, (long)Nn * D, (long)Mpad * D, xblocks, w, wt);

  // fused aggregate + GEMM + bias + relu
  hipLaunchKernelGGL(k_fused, dim3(M32), dim3(256), 0, stream, xb, wt, rp2, ecol,
                     bias, out, Nn);
}